// Round 5
// baseline (341.003 us; speedup 1.0000x reference)
//
#include <hip/hip_runtime.h>

// SynthMorphLoss: soft-dice over int32 label maps + diffusion regularizer.
// B=1, D=160, H=192, W=224, 26 classes (class 0 ignored in dice mean).
// R5: un-fuse (R4 fusion regressed). Force load batching with
// __launch_bounds__(256,4): R3/R4 VGPR counts (28/32) proved the scheduler
// collapsed explicit load batches to ~2 in flight -> ~1 TB/s plateau.
// diff: straight-line, 4 chunks/thread, 16 loads issued before any use;
// flat index masks (w4<55, h<191, d<159) replace wave-shape special cases.

namespace {
constexpr int NC    = 26;
constexpr int Dd    = 160, Hh = 192, Ww = 224;
constexpr int W4    = Ww / 4;                 // 56 float4 per row
constexpr int PL4   = Hh * W4;                // 10752 float4 per (c,d) plane
constexpr int N4F   = 3 * Dd * Hh * W4;       // 5,160,960 (== 5040 * 1024)
constexpr int DIFF_BLOCKS = N4F / 1024;       // 5040, exact cover
constexpr int N4L   = Dd * Hh * Ww / 4;       // 1,720,320 int4 per label map
constexpr int JSTRIDE = 33;                   // joint-hist row stride
constexpr int NBINS   = NC * JSTRIDE;         // 858
constexpr int HIST_BLOCKS = 840;              // 840*256*8 == N4L exact
constexpr int HT          = HIST_BLOCKS * 256;
}

__global__ void init_ws_kernel(unsigned int* __restrict__ joint,
                               double* __restrict__ sums) {
    int i = blockIdx.x * blockDim.x + threadIdx.x;
    if (i < NBINS) joint[i] = 0u;
    if (i < 3)     sums[i]  = 0.0;
}

// Joint histogram: 16 independent int4 loads batched, then 32 LDS atomics.
__global__ __launch_bounds__(256, 4) void hist_kernel(
        const int4* __restrict__ f4,
        const int4* __restrict__ m4,
        unsigned int* __restrict__ gj) {
    __shared__ unsigned int h[NBINS];
    for (int i = threadIdx.x; i < NBINS; i += 256) h[i] = 0u;
    __syncthreads();

    const int g = blockIdx.x * 256 + threadIdx.x;
    int4 a0 = f4[g];
    int4 a1 = f4[g + HT];
    int4 a2 = f4[g + 2 * HT];
    int4 a3 = f4[g + 3 * HT];
    int4 a4 = f4[g + 4 * HT];
    int4 a5 = f4[g + 5 * HT];
    int4 a6 = f4[g + 6 * HT];
    int4 a7 = f4[g + 7 * HT];
    int4 b0 = m4[g];
    int4 b1 = m4[g + HT];
    int4 b2 = m4[g + 2 * HT];
    int4 b3 = m4[g + 3 * HT];
    int4 b4 = m4[g + 4 * HT];
    int4 b5 = m4[g + 5 * HT];
    int4 b6 = m4[g + 6 * HT];
    int4 b7 = m4[g + 7 * HT];

#define JACC(A, B)                                   \
    atomicAdd(&h[(A).x * JSTRIDE + (B).x], 1u);      \
    atomicAdd(&h[(A).y * JSTRIDE + (B).y], 1u);      \
    atomicAdd(&h[(A).z * JSTRIDE + (B).z], 1u);      \
    atomicAdd(&h[(A).w * JSTRIDE + (B).w], 1u);
    JACC(a0, b0) JACC(a1, b1) JACC(a2, b2) JACC(a3, b3)
    JACC(a4, b4) JACC(a5, b5) JACC(a6, b6) JACC(a7, b7)
#undef JACC

    __syncthreads();
    for (int i = threadIdx.x; i < NBINS; i += 256) {
        unsigned int v = h[i];
        if (v) atomicAdd(&gj[i], v);
    }
}

// Diffusion: straight-line, exact cover. Chunk c of thread t in block b is
// float4 index b*1024 + c*256 + t. Streams: a=v[i], n=v[i+1] (dx crossing),
// y=v[i+56] (dy), z=v[i+10752] (dz); n/y/z are L1/L2 hits. Validity by
// flat-index masks; neighbor addresses clamped at the array end.
__global__ __launch_bounds__(256, 4) void diff_kernel(
        const float4* __restrict__ v4,
        double* __restrict__ gs) {
    const int i0 = blockIdx.x * 1024 + threadIdx.x;
    const int i1 = i0 + 256, i2 = i0 + 512, i3 = i0 + 768;

    // ---- issue all 16 loads before any consumption ----
    float4 a0 = v4[i0];
    float4 a1 = v4[i1];
    float4 a2 = v4[i2];
    float4 a3 = v4[i3];
    float4 n0 = v4[min(i0 + 1, N4F - 1)];
    float4 n1 = v4[min(i1 + 1, N4F - 1)];
    float4 n2 = v4[min(i2 + 1, N4F - 1)];
    float4 n3 = v4[min(i3 + 1, N4F - 1)];
    float4 y0 = v4[min(i0 + W4, N4F - 1)];
    float4 y1 = v4[min(i1 + W4, N4F - 1)];
    float4 y2 = v4[min(i2 + W4, N4F - 1)];
    float4 y3 = v4[min(i3 + W4, N4F - 1)];
    float4 z0 = v4[min(i0 + PL4, N4F - 1)];
    float4 z1 = v4[min(i1 + PL4, N4F - 1)];
    float4 z2 = v4[min(i2 + PL4, N4F - 1)];
    float4 z3 = v4[min(i3 + PL4, N4F - 1)];

    float sx = 0.f, sy = 0.f, sz = 0.f;
#define CHUNK(I, A, N, Y, Z)                                                  \
    {                                                                         \
        const int w4 = (I) % W4;                                              \
        const int r  = (I) / W4;                                              \
        const int h  = r % Hh;                                                \
        const int d  = (r / Hh) % Dd;                                         \
        float d1 = (A).y - (A).x, d2 = (A).z - (A).y, d3 = (A).w - (A).z;     \
        float d4 = (N).x - (A).w;                                             \
        sx += d1 * d1 + d2 * d2 + d3 * d3;                                    \
        sx += (w4 < W4 - 1) ? d4 * d4 : 0.f;                                  \
        float e0 = (Y).x - (A).x, e1 = (Y).y - (A).y;                         \
        float e2 = (Y).z - (A).z, e3 = (Y).w - (A).w;                         \
        float s4 = e0 * e0 + e1 * e1 + e2 * e2 + e3 * e3;                     \
        sy += (h < Hh - 1) ? s4 : 0.f;                                        \
        float f0 = (Z).x - (A).x, f1 = (Z).y - (A).y;                         \
        float f2 = (Z).z - (A).z, f3 = (Z).w - (A).w;                         \
        float t4 = f0 * f0 + f1 * f1 + f2 * f2 + f3 * f3;                     \
        sz += (d < Dd - 1) ? t4 : 0.f;                                        \
    }
    CHUNK(i0, a0, n0, y0, z0)
    CHUNK(i1, a1, n1, y1, z1)
    CHUNK(i2, a2, n2, y2, z2)
    CHUNK(i3, a3, n3, y3, z3)
#undef CHUNK

    // wave64 shuffle reduction, then LDS across the block's 4 waves
    #pragma unroll
    for (int off = 32; off > 0; off >>= 1) {
        sx += __shfl_down(sx, off);
        sy += __shfl_down(sy, off);
        sz += __shfl_down(sz, off);
    }
    __shared__ float px[4], py[4], pz[4];
    const int lane = threadIdx.x & 63;
    const int wid  = threadIdx.x >> 6;
    if (lane == 0) { px[wid] = sx; py[wid] = sy; pz[wid] = sz; }
    __syncthreads();
    if (threadIdx.x == 0) {
        atomicAdd(&gs[0], (double)(px[0] + px[1] + px[2] + px[3]));
        atomicAdd(&gs[1], (double)(py[0] + py[1] + py[2] + py[3]));
        atomicAdd(&gs[2], (double)(pz[0] + pz[1] + pz[2] + pz[3]));
    }
}

__global__ void finalize_kernel(const unsigned int* __restrict__ gj,
                                const double* __restrict__ gs,
                                float* __restrict__ out) {
    int lane = threadIdx.x & 63;
    float term = 0.f;
    if (lane >= 1 && lane < NC) {
        float fv = 0.f, mv = 0.f;
        #pragma unroll
        for (int m = 0; m < NC; ++m) fv += (float)gj[lane * JSTRIDE + m];
        #pragma unroll
        for (int f = 0; f < NC; ++f) mv += (float)gj[f * JSTRIDE + lane];
        float iv = (float)gj[lane * JSTRIDE + lane];
        term = (2.f * iv + 1e-5f) / (fv + mv + 1e-5f);
    }
    #pragma unroll
    for (int off = 32; off > 0; off >>= 1) term += __shfl_down(term, off);
    if (threadIdx.x == 0 && blockIdx.x == 0) {
        float sim = 1.f - term * (1.f / 25.f);
        double mdx = gs[0] / ((double)3 * Dd * Hh * (Ww - 1));
        double mdy = gs[1] / ((double)3 * Dd * (Hh - 1) * Ww);
        double mdz = gs[2] / ((double)3 * (Dd - 1) * Hh * Ww);
        float smooth = (float)((mdx + mdy + mdz) / 3.0);
        out[0] = sim + smooth;
        out[1] = sim;
        out[2] = smooth;
    }
}

extern "C" void kernel_launch(void* const* d_in, const int* in_sizes, int n_in,
                              void* d_out, int out_size, void* d_ws, size_t ws_size,
                              hipStream_t stream) {
    const int*   fl = (const int*)d_in[0];
    const int*   ml = (const int*)d_in[1];
    const float* vf = (const float*)d_in[2];
    float* out = (float*)d_out;

    // workspace: [0, 3432) joint counts (858 uints); [3584, 3608) double sums[3]
    unsigned int* joint = (unsigned int*)d_ws;
    double*       sums  = (double*)((char*)d_ws + 3584);

    init_ws_kernel<<<1, 1024, 0, stream>>>(joint, sums);
    hist_kernel<<<HIST_BLOCKS, 256, 0, stream>>>((const int4*)fl, (const int4*)ml, joint);
    diff_kernel<<<DIFF_BLOCKS, 256, 0, stream>>>((const float4*)vf, sums);
    finalize_kernel<<<1, 64, 0, stream>>>(joint, sums, out);
}

// Round 6
// 205.007 us; speedup vs baseline: 1.6634x; 1.6634x over previous
//
#include <hip/hip_runtime.h>

// SynthMorphLoss: soft-dice over int32 label maps + diffusion regularizer.
// B=1, D=160, H=192, W=224, 26 classes (class 0 ignored in dice mean).
// R6: z-carry diff. Empirical invariant across R1-R5: wave-level load BYTES
// flow at ~1.6-2.1 TB/s regardless of structure/cache-level => duration is
// proportional to lane-bytes loaded. So: carry the previous plane's rows in
// registers (dz free), load each plane slab once + 1 dy-halo row per step.
// Re-load factor 1.37x (114 MB) vs R3's 2.17x (178 MB).

namespace {
constexpr int NC    = 26;
constexpr int Dd    = 160, Hh = 192, Ww = 224;
constexpr int W4    = Ww / 4;                 // 56 float4 per row
constexpr int PL4   = Hh * W4;                // 10752 float4 per (c,d) plane
constexpr int N4L   = Dd * Hh * Ww / 4;       // 1,720,320 int4 per label map
constexpr int JSTRIDE = 33;                   // joint-hist row stride
constexpr int NBINS   = NC * JSTRIDE;         // 858
constexpr int HIST_BLOCKS = 840;              // 840*256*8 == N4L exact
constexpr int HT          = HIST_BLOCKS * 256;
// diff decomposition: wave owns (c, 6-row h-slab, 5-plane d-chunk)
constexpr int SLAB    = 6;                    // rows per wave
constexpr int SLABS   = Hh / SLAB;            // 32
constexpr int SGRPS   = SLABS / 4;            // 8 slab-groups (4 waves/block)
constexpr int DCH     = 5;                    // d-steps per wave
constexpr int DCHUNKS = Dd / DCH;             // 32
constexpr int DIFF_BLOCKS = 3 * DCHUNKS * SGRPS;   // 768 == 3 * 256 exactly
}

__global__ void init_ws_kernel(unsigned int* __restrict__ joint,
                               double* __restrict__ sums) {
    int i = blockIdx.x * blockDim.x + threadIdx.x;
    if (i < NBINS) joint[i] = 0u;
    if (i < 3)     sums[i]  = 0.0;
}

// Joint histogram (unchanged from R5 for clean attribution).
__global__ __launch_bounds__(256, 4) void hist_kernel(
        const int4* __restrict__ f4,
        const int4* __restrict__ m4,
        unsigned int* __restrict__ gj) {
    __shared__ unsigned int h[NBINS];
    for (int i = threadIdx.x; i < NBINS; i += 256) h[i] = 0u;
    __syncthreads();

    const int g = blockIdx.x * 256 + threadIdx.x;
    int4 a0 = f4[g];
    int4 a1 = f4[g + HT];
    int4 a2 = f4[g + 2 * HT];
    int4 a3 = f4[g + 3 * HT];
    int4 a4 = f4[g + 4 * HT];
    int4 a5 = f4[g + 5 * HT];
    int4 a6 = f4[g + 6 * HT];
    int4 a7 = f4[g + 7 * HT];
    int4 b0 = m4[g];
    int4 b1 = m4[g + HT];
    int4 b2 = m4[g + 2 * HT];
    int4 b3 = m4[g + 3 * HT];
    int4 b4 = m4[g + 4 * HT];
    int4 b5 = m4[g + 5 * HT];
    int4 b6 = m4[g + 6 * HT];
    int4 b7 = m4[g + 7 * HT];

#define JACC(A, B)                                   \
    atomicAdd(&h[(A).x * JSTRIDE + (B).x], 1u);      \
    atomicAdd(&h[(A).y * JSTRIDE + (B).y], 1u);      \
    atomicAdd(&h[(A).z * JSTRIDE + (B).z], 1u);      \
    atomicAdd(&h[(A).w * JSTRIDE + (B).w], 1u);
    JACC(a0, b0) JACC(a1, b1) JACC(a2, b2) JACC(a3, b3)
    JACC(a4, b4) JACC(a5, b5) JACC(a6, b6) JACC(a7, b7)
#undef JACC

    __syncthreads();
    for (int i = threadIdx.x; i < NBINS; i += 256) {
        unsigned int v = h[i];
        if (v) atomicAdd(&gj[i], v);
    }
}

// z-carry diffusion. Wave w of block b owns h-slab [h0,h0+6) of channel c,
// planes d0..d0+4. Carries current plane's 6 rows in registers; per d-step
// loads the next plane's 6 rows + 1 dy-halo row (7 x 896 B). dz = next-prev
// from registers. All validity masks wave-uniform except the lane dx mask.
__global__ __launch_bounds__(256, 3) void diff_kernel(
        const float4* __restrict__ v4,
        double* __restrict__ gs) {
    const int lane = threadIdx.x & 63;
    const int wid  = threadIdx.x >> 6;
    const int b    = blockIdx.x;
    const int c      = b / (DCHUNKS * SGRPS);     // b / 256
    const int rem    = b % (DCHUNKS * SGRPS);
    const int dchunk = rem / SGRPS;
    const int sgrp   = rem % SGRPS;
    const int slab   = sgrp * 4 + wid;
    const int h0     = slab * SLAB;
    const int d0     = dchunk * DCH;
    const bool al    = (lane < W4);
    const bool hv    = (h0 + SLAB < Hh);          // dy-halo row exists
    const int  l     = al ? lane : (W4 - 1);      // clamp inactive lanes

    size_t cur = ((size_t)(c * Dd + d0) * Hh + h0) * W4 + l;

    float4 p0 = v4[cur];
    float4 p1 = v4[cur + W4];
    float4 p2 = v4[cur + 2 * W4];
    float4 p3 = v4[cur + 3 * W4];
    float4 p4 = v4[cur + 4 * W4];
    float4 p5 = v4[cur + 5 * W4];

    float sx = 0.f, sy = 0.f, sz = 0.f;
    const int haloOff = (hv ? SLAB : SLAB - 1) * W4;   // clamp: masked anyway

    for (int k = 0; k < DCH; ++k) {
        const int d = d0 + k;
        const bool dzv = (d < Dd - 1);            // wave-uniform
        float4 hl = v4[cur + haloOff];
        float4 n0 = p0, n1 = p1, n2 = p2, n3 = p3, n4 = p4, n5 = p5;
        if (dzv) {
            const size_t nb = cur + PL4;
            n0 = v4[nb];
            n1 = v4[nb + W4];
            n2 = v4[nb + 2 * W4];
            n3 = v4[nb + 3 * W4];
            n4 = v4[nb + 4 * W4];
            n5 = v4[nb + 5 * W4];
        }

        // dx: 3 interior diffs + crossing diff (lane mask)
#define DX(P)                                                                  \
        {                                                                      \
            float d1 = (P).y - (P).x, d2 = (P).z - (P).y, d3 = (P).w - (P).z;  \
            sx += d1 * d1 + d2 * d2 + d3 * d3;                                 \
            float nx = __shfl_down((P).x, 1);                                  \
            float d4 = nx - (P).w;                                             \
            sx += (lane < W4 - 1) ? d4 * d4 : 0.f;                             \
        }
        DX(p0) DX(p1) DX(p2) DX(p3) DX(p4) DX(p5)
#undef DX
        // dy: rows 0..4 within slab; row 5 against halo (wave-uniform hv)
#define DY(A, B)                                                               \
        {                                                                      \
            float e0 = (B).x - (A).x, e1 = (B).y - (A).y;                      \
            float e2 = (B).z - (A).z, e3 = (B).w - (A).w;                      \
            sy += e0 * e0 + e1 * e1 + e2 * e2 + e3 * e3;                       \
        }
        DY(p0, p1) DY(p1, p2) DY(p2, p3) DY(p3, p4) DY(p4, p5)
        if (hv) DY(p5, hl)
#undef DY
        // dz: next plane minus current (registers), wave-uniform dzv
        if (dzv) {
#define DZ(A, B)                                                               \
            {                                                                  \
                float e0 = (B).x - (A).x, e1 = (B).y - (A).y;                  \
                float e2 = (B).z - (A).z, e3 = (B).w - (A).w;                  \
                sz += e0 * e0 + e1 * e1 + e2 * e2 + e3 * e3;                   \
            }
            DZ(p0, n0) DZ(p1, n1) DZ(p2, n2) DZ(p3, n3) DZ(p4, n4) DZ(p5, n5)
#undef DZ
        }
        p0 = n0; p1 = n1; p2 = n2; p3 = n3; p4 = n4; p5 = n5;
        cur += PL4;
    }

    if (!al) { sx = 0.f; sy = 0.f; sz = 0.f; }    // clamped lanes: drop dupes

    #pragma unroll
    for (int off = 32; off > 0; off >>= 1) {
        sx += __shfl_down(sx, off);
        sy += __shfl_down(sy, off);
        sz += __shfl_down(sz, off);
    }
    __shared__ float px[4], py[4], pz[4];
    if (lane == 0) { px[wid] = sx; py[wid] = sy; pz[wid] = sz; }
    __syncthreads();
    if (threadIdx.x == 0) {
        atomicAdd(&gs[0], (double)(px[0] + px[1] + px[2] + px[3]));
        atomicAdd(&gs[1], (double)(py[0] + py[1] + py[2] + py[3]));
        atomicAdd(&gs[2], (double)(pz[0] + pz[1] + pz[2] + pz[3]));
    }
}

__global__ void finalize_kernel(const unsigned int* __restrict__ gj,
                                const double* __restrict__ gs,
                                float* __restrict__ out) {
    int lane = threadIdx.x & 63;
    float term = 0.f;
    if (lane >= 1 && lane < NC) {
        float fv = 0.f, mv = 0.f;
        #pragma unroll
        for (int m = 0; m < NC; ++m) fv += (float)gj[lane * JSTRIDE + m];
        #pragma unroll
        for (int f = 0; f < NC; ++f) mv += (float)gj[f * JSTRIDE + lane];
        float iv = (float)gj[lane * JSTRIDE + lane];
        term = (2.f * iv + 1e-5f) / (fv + mv + 1e-5f);
    }
    #pragma unroll
    for (int off = 32; off > 0; off >>= 1) term += __shfl_down(term, off);
    if (threadIdx.x == 0 && blockIdx.x == 0) {
        float sim = 1.f - term * (1.f / 25.f);
        double mdx = gs[0] / ((double)3 * Dd * Hh * (Ww - 1));
        double mdy = gs[1] / ((double)3 * Dd * (Hh - 1) * Ww);
        double mdz = gs[2] / ((double)3 * (Dd - 1) * Hh * Ww);
        float smooth = (float)((mdx + mdy + mdz) / 3.0);
        out[0] = sim + smooth;
        out[1] = sim;
        out[2] = smooth;
    }
}

extern "C" void kernel_launch(void* const* d_in, const int* in_sizes, int n_in,
                              void* d_out, int out_size, void* d_ws, size_t ws_size,
                              hipStream_t stream) {
    const int*   fl = (const int*)d_in[0];
    const int*   ml = (const int*)d_in[1];
    const float* vf = (const float*)d_in[2];
    float* out = (float*)d_out;

    // workspace: [0, 3432) joint counts (858 uints); [3584, 3608) double sums[3]
    unsigned int* joint = (unsigned int*)d_ws;
    double*       sums  = (double*)((char*)d_ws + 3584);

    init_ws_kernel<<<1, 1024, 0, stream>>>(joint, sums);
    hist_kernel<<<HIST_BLOCKS, 256, 0, stream>>>((const int4*)fl, (const int4*)ml, joint);
    diff_kernel<<<DIFF_BLOCKS, 256, 0, stream>>>((const float4*)vf, sums);
    finalize_kernel<<<1, 64, 0, stream>>>(joint, sums, out);
}